// Round 8
// baseline (860.672 us; speedup 1.0000x reference)
//
#include <hip/hip_runtime.h>
#include <hip/hip_bf16.h>

// GlobalFilter: y = irfft2(rfft2(x, ortho) * W, ortho) over axes (1,2)
// == per-channel 14x14 circular conv with real kernel k_c = ifft2(M_c):
//   k_c[p,q] = (1/196) * sum_{u<14,v<8} c_v*(Wr*cos(th) - Wi*st(th)),
//   th = 2*pi*(u*p+v*q)/14, c_v = 1 for v in {0,7} else 2.
//
// v8: one output row per wave (block = 896 thr = 14 waves per (batch,64ch));
// pure f32. Per-step live set: acc[14] + x cur/next[28] + k cur/next[28]
// ~= 95 VGPR < 128 cap. sched_barrier(0) at each r-step end stops the
// scheduler from hoisting loads >1 step ahead (R7: hoisting blew the 128
// cap -> ~110 floats/thread spilled -> 150 MB scratch writes/dispatch).
// Explicit 1-step prefetch does the latency hiding instead.

#define CC 768

// ---------------- Kernel A: plain spatial kernels k[196][768] f32 ----------------
// grid (12 cgroups, 14 p), 896 threads = 14 q x 64 ch.
__global__ __launch_bounds__(896) void gf_build_k(const float* __restrict__ wg,
                                                  float* __restrict__ kbuf) {
    __shared__ float ws[112 * 128];        // [uv][cl][ri], pre-scaled by cv/196
    __shared__ float ct[14], st[14];
    int t = threadIdx.x;
    int c0 = blockIdx.x * 64;
    int p  = blockIdx.y;
    if (t < 14) {
        float ang = 6.283185307179586f * (float)t / 14.0f;
        ct[t] = cosf(ang);
        st[t] = sinf(ang);
    }
    #pragma unroll
    for (int j = 0; j < 16; ++j) {
        int f = t + j * 896;               // 0..14335
        int uv = f >> 7;
        int v = uv & 7;
        float scale = (v == 0 || v == 7) ? (1.0f / 196.0f) : (2.0f / 196.0f);
        ws[f] = wg[(size_t)uv * 1536 + (size_t)c0 * 2 + (f & 127)] * scale;
    }
    __syncthreads();

    int q = t >> 6, cl = t & 63;
    float a = 0.f;
    int up = 0;                            // (u*p) % 14
    #pragma unroll
    for (int u = 0; u < 14; ++u) {
        int r = up;                        // (u*p + v*q) % 14
        #pragma unroll
        for (int v = 0; v < 8; ++v) {
            float wr = ws[(u * 8 + v) * 128 + cl * 2];
            float wi = ws[(u * 8 + v) * 128 + cl * 2 + 1];
            a += wr * ct[r] - wi * st[r];
            r += q; if (r >= 14) r -= 14;
        }
        up += p; if (up >= 14) up -= 14;
    }
    kbuf[(size_t)(p * 14 + q) * CC + c0 + cl] = a;
}

// ---------------- Kernel B: depthwise circular conv, 1 row/wave ----------------
// grid (12 cgroups, 128 batches), 896 threads = 14 waves (one per output row).
// y[b][h][w][c] = sum_r sum_q k[(h-r)%14][q][c] * x[b][r][(w-q)%14][c]
__global__ __launch_bounds__(896) void gf_conv8(const float* __restrict__ x,
                                                const float* __restrict__ kbuf,
                                                float* __restrict__ y) {
    int b  = blockIdx.y;
    int c0 = blockIdx.x * 64;
    int t  = threadIdx.x;
    int cl = t & 63;                       // lane = channel
    int h  = t >> 6;                       // wave id = output row 0..13

    const float* xb = x + (size_t)b * 196 * CC + c0 + cl;
    const float* kb = kbuf + c0 + cl;
    float* yb = y + (size_t)b * 196 * CC + c0 + cl;

    float acc[14];
    #pragma unroll
    for (int w = 0; w < 14; ++w) acc[w] = 0.f;

    float xf[2][14], kf[2][14];            // cur/next double buffers

    // prologue: x row 0; k row d=h (wave-uniform row index)
    #pragma unroll
    for (int w = 0; w < 14; ++w) xf[0][w] = xb[w * CC];
    #pragma unroll
    for (int q = 0; q < 14; ++q) kf[0][q] = kb[(h * 14 + q) * CC];

    int d = h;                             // k-row = (h - r) mod 14
    #pragma unroll
    for (int r = 0; r < 14; ++r) {
        const int xc = r & 1, xn = xc ^ 1; // static after unroll

        if (r < 13) {                      // prefetch next x row + next k row
            #pragma unroll
            for (int w = 0; w < 14; ++w) xf[xn][w] = xb[((r + 1) * 14 + w) * CC];
            int dn = (d == 0) ? 13 : d - 1;
            #pragma unroll
            for (int q = 0; q < 14; ++q) kf[xn][q] = kb[(dn * 14 + q) * CC];
            d = dn;
        }

        #pragma unroll
        for (int q = 0; q < 14; ++q) {
            float kv = kf[xc][q];
            #pragma unroll
            for (int w = 0; w < 14; ++w) {
                int src = w - q; if (src < 0) src += 14;
                acc[w] += kv * xf[xc][src];
            }
        }
        // fence: keep the scheduler from hoisting step r+2 loads into this
        // step's compute (register-pressure blowup -> spill, R5/R6/R7).
        __builtin_amdgcn_sched_barrier(0);
    }

    #pragma unroll
    for (int w = 0; w < 14; ++w) yb[(h * 14 + w) * CC] = acc[w];
}

extern "C" void kernel_launch(void* const* d_in, const int* in_sizes, int n_in,
                              void* d_out, int out_size, void* d_ws, size_t ws_size,
                              hipStream_t stream) {
    const float* x = (const float*)d_in[0];
    const float* w = (const float*)d_in[1];
    float* y = (float*)d_out;
    float* kbuf = (float*)d_ws;            // 196*768*4 = 602,112 B

    gf_build_k<<<dim3(12, 14), dim3(896), 0, stream>>>(w, kbuf);

    dim3 grid(12, 128);                    // cgroup, batch
    gf_conv8<<<grid, dim3(896), 0, stream>>>(x, kbuf, y);
}

// Round 9
// 122.522 us; speedup vs baseline: 7.0247x; 7.0247x over previous
//
#include <hip/hip_runtime.h>
#include <hip/hip_bf16.h>

// GlobalFilter: y = irfft2(rfft2(x, ortho) * W, ortho) over axes (1,2)
// == per-channel 14x14 circular conv with real kernel k_c = ifft2(M_c):
//   k_c[p,q] = (1/196) * sum_{u<14,v<8} c_v*(Wr*cos(th) - Wi*sin(th)),
//   th = 2*pi*(u*p+v*q)/14, c_v = 1 for v in {0,7} else 2.
//
// v9: 1-wave blocks (64 thr), launch_bounds(64) + amdgpu_waves_per_eu(1,4):
// min=1 -> RA never forced to spill (R5-R8 all died to heuristic VGPR caps:
// 64/128 -> 100-1500 MB scratch writes); max=4 -> 128-reg pressure target,
// live set ~100 fits. One wave = output rows (2g, 2g+1) of one (batch, 64ch).
// fdot2 over q-pairs: kq[d][t] = half2(k[d][2t], k[d][2t+1]) (kernel A),
// xp[m] = pkrtz(x[m], x[m-1]); acc[w] += dot2(kq[d][t], xp[(w-2t)%14]).
// f32 accumulate. XCD-swizzled linear grid: 7 g-waves of a (b,cg) land on
// one XCD -> x HBM-fetched once, L2-served 6x.

typedef _Float16 h2 __attribute__((ext_vector_type(2)));

#define CC 768

// ---------------- Kernel A: q-paired spatial kernels kq[14][7][768] u32 ----------------
// grid (12 cgroups, 14 d), 448 threads = 7 t x 64 ch.
__global__ __launch_bounds__(448) void gf_build_kq(const float* __restrict__ wg,
                                                   unsigned int* __restrict__ kq) {
    __shared__ float ws[112 * 128];        // [uv][cl][ri], pre-scaled by cv/196
    __shared__ float ct[14], st[14];
    int t = threadIdx.x;
    int c0 = blockIdx.x * 64;
    int d  = blockIdx.y;
    if (t < 14) {
        float ang = 6.283185307179586f * (float)t / 14.0f;
        ct[t] = cosf(ang);
        st[t] = sinf(ang);
    }
    #pragma unroll
    for (int j = 0; j < 32; ++j) {
        int f = t + j * 448;               // 0..14335
        int uv = f >> 7;
        int v = uv & 7;
        float scale = (v == 0 || v == 7) ? (1.0f / 196.0f) : (2.0f / 196.0f);
        ws[f] = wg[(size_t)uv * 1536 + (size_t)c0 * 2 + (f & 127)] * scale;
    }
    __syncthreads();

    int tt = t >> 6, cl = t & 63;          // tt = q-pair 0..6
    int q0 = 2 * tt, q1 = 2 * tt + 1;
    float a0 = 0.f, a1 = 0.f;
    int ud = 0;                            // (u*d) % 14
    #pragma unroll
    for (int u = 0; u < 14; ++u) {
        int r0 = ud, r1 = ud;
        #pragma unroll
        for (int v = 0; v < 8; ++v) {
            float wr = ws[(u * 8 + v) * 128 + cl * 2];
            float wi = ws[(u * 8 + v) * 128 + cl * 2 + 1];
            a0 += wr * ct[r0] - wi * st[r0];
            a1 += wr * ct[r1] - wi * st[r1];
            r0 += q0; if (r0 >= 14) r0 -= 14;
            r1 += q1; if (r1 >= 14) r1 -= 14;
        }
        ud += d; if (ud >= 14) ud -= 14;
    }
    kq[(size_t)(d * 7 + tt) * CC + c0 + cl] =
        __builtin_bit_cast(unsigned int, __builtin_amdgcn_cvt_pkrtz(a0, a1));
}

// ---------------- Kernel B: depthwise circular conv, fdot2, 1 wave/block ----------------
// grid 10752 linear (XCD-swizzled). wave -> (cg, b, g): rows 2g, 2g+1.
__global__ __launch_bounds__(64)
__attribute__((amdgpu_waves_per_eu(1, 4)))
void gf_conv9(const float* __restrict__ x,
              const unsigned int* __restrict__ kq,
              float* __restrict__ y) {
    // XCD swizzle: HW round-robins consecutive blockIdx across 8 XCDs;
    // remap so each XCD gets a contiguous 1344-slot chunk (10752 = 8*1344).
    int wg  = blockIdx.x;
    int swz = (wg & 7) * 1344 + (wg >> 3);
    int cg  = swz / 896;                   // 0..11   (896 = 128 b * 7 g)
    int rem = swz - cg * 896;
    int b   = rem / 7;                     // 0..127
    int g   = rem - b * 7;                 // 0..6
    int c0  = cg * 64;
    int cl  = threadIdx.x;                 // lane = channel
    int h0  = 2 * g;                       // output rows h0, h0+1

    const float* xb = x + (size_t)b * 196 * CC + c0 + cl;
    const unsigned int* kb = kq + c0 + cl;
    float* yb = y + (size_t)b * 196 * CC + c0 + cl;

    float        xf[2][14];                // x row double buffer (f32)
    unsigned int kr[3][14 / 2 * 2];        // 3-slot rotation, 7 u32 used per slot
    float acc0[14], acc1[14];
    #pragma unroll
    for (int w = 0; w < 14; ++w) { acc0[w] = 0.f; acc1[w] = 0.f; }

    // prologue: x row 0; k rows h0+1 -> slot 0, h0 -> slot 1
    #pragma unroll
    for (int w = 0; w < 14; ++w) xf[0][w] = xb[w * CC];
    #pragma unroll
    for (int t = 0; t < 7; ++t) kr[0][t] = kb[((h0 + 1) * 7 + t) * CC];
    #pragma unroll
    for (int t = 0; t < 7; ++t) kr[1][t] = kb[(h0 * 7 + t) * CC];

    #pragma unroll
    for (int r = 0; r < 14; ++r) {
        const int xc = r & 1, xn = xc ^ 1;           // static after unroll
        const int sd0 = (r + 1) % 3;                 // slot of row d0 = h0-r
        const int sd1 = r % 3;                       // slot of row d0+1

        if (r < 13) {                                // 1-step prefetch
            #pragma unroll
            for (int w = 0; w < 14; ++w) xf[xn][w] = xb[((r + 1) * 14 + w) * CC];
            int dn = h0 - 1 - r; if (dn < 0) dn += 14;
            #pragma unroll
            for (int t = 0; t < 7; ++t) kr[(r + 2) % 3][t] = kb[(dn * 7 + t) * CC];
        }

        // xp[m] = (x[m], x[(m-1)%14]) packed f16
        unsigned int xp[14];
        #pragma unroll
        for (int m = 0; m < 14; ++m) {
            int m1 = (m == 0) ? 13 : m - 1;
            xp[m] = __builtin_bit_cast(unsigned int,
                        __builtin_amdgcn_cvt_pkrtz(xf[xc][m], xf[xc][m1]));
        }

        #pragma unroll
        for (int t = 0; t < 7; ++t) {
            h2 kv0 = __builtin_bit_cast(h2, kr[sd0][t]);   // row d0   -> acc0
            h2 kv1 = __builtin_bit_cast(h2, kr[sd1][t]);   // row d0+1 -> acc1
            #pragma unroll
            for (int w = 0; w < 14; ++w) {
                int m = w - 2 * t; if (m < 0) m += 14;     // compile-time
                h2 xv = __builtin_bit_cast(h2, xp[m]);
                acc0[w] = __builtin_amdgcn_fdot2(kv0, xv, acc0[w], false);
                acc1[w] = __builtin_amdgcn_fdot2(kv1, xv, acc1[w], false);
            }
        }
        // fence: keep scheduler from hoisting step r+2 loads (pressure blowup)
        __builtin_amdgcn_sched_barrier(0);
    }

    #pragma unroll
    for (int w = 0; w < 14; ++w) {
        yb[(h0 * 14 + w) * CC]       = acc0[w];
        yb[((h0 + 1) * 14 + w) * CC] = acc1[w];
    }
}

extern "C" void kernel_launch(void* const* d_in, const int* in_sizes, int n_in,
                              void* d_out, int out_size, void* d_ws, size_t ws_size,
                              hipStream_t stream) {
    const float* x = (const float*)d_in[0];
    const float* w = (const float*)d_in[1];
    float* y = (float*)d_out;
    unsigned int* kbuf = (unsigned int*)d_ws;   // 14*7*768*4 = 301,056 B

    gf_build_kq<<<dim3(12, 14), dim3(448), 0, stream>>>(w, kbuf);

    gf_conv9<<<dim3(10752), dim3(64), 0, stream>>>(x, kbuf, y);
}